// Round 3
// baseline (113.617 us; speedup 1.0000x reference)
//
#include <hip/hip_runtime.h>
#include <hip/hip_bf16.h>

#define BT 262144
#define BLOCK 256
#define ROWS_PER_BLOCK 64

typedef __attribute__((ext_vector_type(8))) short short8;
typedef __attribute__((ext_vector_type(4))) float f32x4;

__device__ __forceinline__ unsigned short f2bf(float f) {
  union { __hip_bfloat16 b; unsigned short u; } v;
  v.b = __float2bfloat16(f);
  return v.u;
}
__device__ __forceinline__ float frcp(float x) { return __builtin_amdgcn_rcpf(x); }
__device__ __forceinline__ float sigm(float x) { return frcp(1.0f + __expf(-x)); }
__device__ __forceinline__ float tanh_(float x) {
  float e = __expf(-2.0f * x);
  return (1.0f - e) * frcp(1.0f + e);
}

// Prep: W_eff = W_ih @ W_in, b_eff = b_ih + b_hh + W_ih @ b_in.
// Fragment layout optimized for the t-quad gate loop: element index
//   id = ((((tq*2 + ks)*2 + op)*4 + g)*64 + l)*8 + j      (32768 elements)
//   op: 0 = W_eff (obs operand), 1 = W_hh (h operand)
//   value = W[n][k], n = (g*4+tq)*16 + (l&15), k = ks*32 + (l>>4)*8 + j
// Each t-quad reads a CONTIGUOUS 16 KB block -> L1-resident streaming.
// wO fragments at elements 32768..33791: (ks*64 + l)*8 + j, n = l&15.
__global__ void prep_kernel(const float* __restrict__ W_in, const float* __restrict__ b_in,
                            const float* __restrict__ W_ih, const float* __restrict__ W_hh,
                            const float* __restrict__ b_ih, const float* __restrict__ b_hh,
                            const float* __restrict__ W_out,
                            unsigned short* __restrict__ wsW, float* __restrict__ ws_beff) {
  int id = blockIdx.x * blockDim.x + threadIdx.x;
  if (id < 32768) {                       // W_eff / W_hh fragments
    int j = id & 7, l = (id >> 3) & 63, g = (id >> 9) & 3, op = (id >> 11) & 1;
    int ks = (id >> 12) & 1, tq = (id >> 13) & 3;
    int n = (g * 4 + tq) * 16 + (l & 15);
    int k = ks * 32 + (l >> 4) * 8 + j;
    float s;
    if (op == 0) {
      s = 0.f;
      #pragma unroll 8
      for (int h = 0; h < 64; ++h) s = fmaf(W_ih[n * 64 + h], W_in[h * 64 + k], s);
    } else {
      s = W_hh[n * 64 + k];
    }
    wsW[id] = f2bf(s);
  } else if (id < 33792) {                // W_out fragments (1 ntile, 2 ksteps)
    int e = id - 32768;
    int j = e & 7, l = (e >> 3) & 63, ks = e >> 9;
    int n = l & 15;
    int k = ks * 32 + (l >> 4) * 8 + j;
    wsW[id] = f2bf(W_out[n * 64 + k]);
  } else if (id < 34048) {                // b_eff
    int n = id - 33792;
    float s = b_ih[n] + b_hh[n];
    #pragma unroll 8
    for (int h = 0; h < 64; ++h) s = fmaf(W_ih[n * 64 + h], b_in[h], s);
    ws_beff[n] = s;
  }
}

__device__ __forceinline__ short8 pack8(float4 lo, float4 hi) {
  short8 r;
  r[0] = (short)f2bf(lo.x); r[1] = (short)f2bf(lo.y);
  r[2] = (short)f2bf(lo.z); r[3] = (short)f2bf(lo.w);
  r[4] = (short)f2bf(hi.x); r[5] = (short)f2bf(hi.y);
  r[6] = (short)f2bf(hi.z); r[7] = (short)f2bf(hi.w);
  return r;
}

// Wave-autonomous: no barriers, no weight staging. B-fragments come straight
// from global (L1/L2-hot: every block reads the same 66 KB). Only LDS is the
// per-wave 2 KB h_new transpose buffer.
__global__ __launch_bounds__(BLOCK, 5) void lstm_main(
    const float* __restrict__ obs, const float* __restrict__ h0,
    const float* __restrict__ c0, const float* __restrict__ b_out,
    const unsigned short* __restrict__ wsW, const float* __restrict__ ws_beff,
    float* __restrict__ out) {
  __shared__ __attribute__((aligned(16))) unsigned short hfrag[4][1024];

  const int tid = threadIdx.x;
  const int wv = tid >> 6;
  const int lane = tid & 63;
  const int l16 = lane & 15;
  const int q = lane >> 4;                 // 0..3
  const size_t rowbase = (size_t)blockIdx.x * ROWS_PER_BLOCK + (size_t)wv * 16;

  // issue all streaming loads up front (obs/h0 A-operands + c0)
  const float* po = obs + (rowbase + l16) * 64 + q * 8;
  const float* ph = h0 + (rowbase + l16) * 64 + q * 8;
  float4 ro0 = *(const float4*)(po);
  float4 ro1 = *(const float4*)(po + 4);
  float4 ro2 = *(const float4*)(po + 32);
  float4 ro3 = *(const float4*)(po + 36);
  float4 rh0 = *(const float4*)(ph);
  float4 rh1 = *(const float4*)(ph + 4);
  float4 rh2 = *(const float4*)(ph + 32);
  float4 rh3 = *(const float4*)(ph + 36);

  float cold[16];
  #pragma unroll
  for (int tq = 0; tq < 4; ++tq)
    #pragma unroll
    for (int r = 0; r < 4; ++r)
      cold[tq * 4 + r] = c0[(rowbase + (size_t)(4 * q + r)) * 64 + tq * 16 + l16];

  float boA = b_out[l16];

  short8 aObs[2], aH[2];
  aObs[0] = pack8(ro0, ro1); aObs[1] = pack8(ro2, ro3);
  aH[0]   = pack8(rh0, rh1); aH[1]   = pack8(rh2, rh3);

  const short8* W = (const short8*)wsW;
  float* out_act = out;
  float* out_h = out + (size_t)BT * 16;
  float* out_c = out + (size_t)BT * 80;
  unsigned short* hbuf = &hfrag[wv][0];

  #pragma unroll
  for (int tq = 0; tq < 4; ++tq) {
    float bi = ws_beff[(0 * 4 + tq) * 16 + l16];
    float bf = ws_beff[(1 * 4 + tq) * 16 + l16];
    float bg = ws_beff[(2 * 4 + tq) * 16 + l16];
    float bo = ws_beff[(3 * 4 + tq) * 16 + l16];
    f32x4 ai = (f32x4){bi, bi, bi, bi};
    f32x4 af = (f32x4){bf, bf, bf, bf};
    f32x4 ag = (f32x4){bg, bg, bg, bg};
    f32x4 ao = (f32x4){bo, bo, bo, bo};
    #pragma unroll
    for (int ks = 0; ks < 2; ++ks) {
      const short8* pE = W + ((tq * 2 + ks) * 2 + 0) * 256;
      const short8* pH = W + ((tq * 2 + ks) * 2 + 1) * 256;
      ai = __builtin_amdgcn_mfma_f32_16x16x32_bf16(aObs[ks], pE[0 * 64 + lane], ai, 0, 0, 0);
      af = __builtin_amdgcn_mfma_f32_16x16x32_bf16(aObs[ks], pE[1 * 64 + lane], af, 0, 0, 0);
      ag = __builtin_amdgcn_mfma_f32_16x16x32_bf16(aObs[ks], pE[2 * 64 + lane], ag, 0, 0, 0);
      ao = __builtin_amdgcn_mfma_f32_16x16x32_bf16(aObs[ks], pE[3 * 64 + lane], ao, 0, 0, 0);
      ai = __builtin_amdgcn_mfma_f32_16x16x32_bf16(aH[ks], pH[0 * 64 + lane], ai, 0, 0, 0);
      af = __builtin_amdgcn_mfma_f32_16x16x32_bf16(aH[ks], pH[1 * 64 + lane], af, 0, 0, 0);
      ag = __builtin_amdgcn_mfma_f32_16x16x32_bf16(aH[ks], pH[2 * 64 + lane], ag, 0, 0, 0);
      ao = __builtin_amdgcn_mfma_f32_16x16x32_bf16(aH[ks], pH[3 * 64 + lane], ao, 0, 0, 0);
    }
    // elementwise LSTM cell; D layout: lane holds row 4*q+r, col tq*16+l16
    #pragma unroll
    for (int r = 0; r < 4; ++r) {
      float iv = sigm(ai[r]);
      float fv = sigm(af[r]);
      float gv = tanh_(ag[r]);
      float ov = sigm(ao[r]);
      size_t m = rowbase + (size_t)(4 * q + r);
      int n = tq * 16 + l16;
      float cnew = fmaf(fv, cold[tq * 4 + r], iv * gv);
      float hnew = ov * tanh_(cnew);
      out_c[m * 64 + n] = cnew;
      out_h[m * 64 + n] = hnew;
      // scatter h_new into A-fragment layout for the W_out MFMA
      int lp = (4 * q + r) + 16 * ((tq & 1) * 2 + (l16 >> 3));
      hbuf[(tq >> 1) * 512 + lp * 8 + (l16 & 7)] = f2bf(hnew);
    }
  }
  // hbuf is per-wave: same-wave ds_write -> ds_read needs no barrier

  // action = tanh(h_new @ W_out^T + b_out); ACTION range [-1,1] => identity map
  f32x4 accA = (f32x4){boA, boA, boA, boA};
  short8 a0 = *(const short8*)(hbuf + lane * 8);
  short8 a1 = *(const short8*)(hbuf + 512 + lane * 8);
  accA = __builtin_amdgcn_mfma_f32_16x16x32_bf16(a0, W[4096 + lane], accA, 0, 0, 0);
  accA = __builtin_amdgcn_mfma_f32_16x16x32_bf16(a1, W[4096 + 64 + lane], accA, 0, 0, 0);
  #pragma unroll
  for (int r = 0; r < 4; ++r) {
    size_t m = rowbase + (size_t)(4 * q + r);
    out_act[m * 16 + l16] = tanh_(accA[r]);
  }
}

extern "C" void kernel_launch(void* const* d_in, const int* in_sizes, int n_in,
                              void* d_out, int out_size, void* d_ws, size_t ws_size,
                              hipStream_t stream) {
  const float* obs  = (const float*)d_in[0];
  const float* h0   = (const float*)d_in[1];
  const float* c0   = (const float*)d_in[2];
  const float* W_in = (const float*)d_in[3];
  const float* b_in = (const float*)d_in[4];
  const float* W_ih = (const float*)d_in[5];
  const float* W_hh = (const float*)d_in[6];
  const float* b_ih = (const float*)d_in[7];
  const float* b_hh = (const float*)d_in[8];
  const float* W_out = (const float*)d_in[9];
  const float* b_out = (const float*)d_in[10];

  unsigned short* wsW = (unsigned short*)d_ws;
  float* ws_beff = (float*)((char*)d_ws + 67584);

  prep_kernel<<<133, 256, 0, stream>>>(W_in, b_in, W_ih, W_hh, b_ih, b_hh, W_out, wsW, ws_beff);
  lstm_main<<<BT / ROWS_PER_BLOCK, BLOCK, 0, stream>>>(obs, h0, c0, b_out, wsW, ws_beff, (float*)d_out);
}